// Round 12
// baseline (824.467 us; speedup 1.0000x reference)
//
#include <hip/hip_runtime.h>

#define H 512
#define MTILE 64
#define NBLK 8192
#define STEPC (2.4f / 63.0f)

typedef _Float16 half8 __attribute__((ext_vector_type(8)));
typedef _Float16 half4_t __attribute__((ext_vector_type(4)));
typedef float floatx16 __attribute__((ext_vector_type(16)));
typedef float floatx4 __attribute__((ext_vector_type(4)));
typedef float floatx2 __attribute__((ext_vector_type(2)));

// fast silu: native exp + fast div. rel-err ~1e-7, negligible vs fp16 rounding.
__device__ inline float silu_f(float x) {
    return __fdividef(x, 1.0f + __expf(-x));
}

// ---- fused prep: blocks 0..1023 -> W image; blocks 1024..1025 -> latw ----
// W image layout: [l][wv][hi][ks][nt][lm][e]  (halves)
//   idx = (l*8+wv)*32768 + hi*16384 + ks*512 + nt*256 + lm*8 + e
__global__ void prep_fused(const float* __restrict__ lat, const float* __restrict__ W0,
                           const float* __restrict__ b0,
                           const float* __restrict__ W1, const float* __restrict__ W2,
                           float* __restrict__ latw, _Float16* __restrict__ ws) {
    __shared__ float sl[H];
    if (blockIdx.x < 1024) {
        const int id = blockIdx.x * 512 + threadIdx.x;   // 0 .. 524287
        const int l = id >> 18;
        const int rem = id & 0x3FFFF;                    // k*512 + n
        const int k = rem >> 9, n = rem & 511;
        const float w = (l == 0 ? W1 : W2)[rem];
        const int ks = k >> 4, hi = (k >> 3) & 1, e = k & 7;
        const int wv = n >> 6, nt = (n >> 5) & 1, lm = n & 31;
        ws[(size_t)(l * 8 + wv) * 32768 + hi * 16384 + ks * 512 + nt * 256 + lm * 8 + e]
            = (_Float16)w;
    } else {
        const int b = blockIdx.x - 1024;
        const int j = threadIdx.x;
        sl[j] = lat[b * H + j];
        __syncthreads();
        float acc = b0[j];
#pragma unroll 8
        for (int d = 0; d < H; ++d) acc += sl[d] * W0[d * H + j];
        latw[b * H + j] = acc;
    }
}

// ---- main fused kernel ----
// R12: BURST SCHEDULE (m201/m218 pattern). R10/R11 fit the serialized-sum
// model exactly: MFMA + L2-W + LDS-A + VALU serialize per-wave when
// fine-interleaved (per-ks: 1330 cyc measured vs 1443 serial vs ~550
// overlapped). Fix per m196/m218 ablations: dense 16-MFMA bursts with all
// operands pre-staged in registers; memory issued in separate clusters;
// counted vmcnt(8) (never 0 mid-loop); setprio role-split; 2 waves/SIMD.
//   * launch_bounds(512,2): 256-reg budget, 1 block/CU.
//   * queues: W 2 supersteps x 4ks x 2nt (64 VGPR), A 2 ss x 4ks x 2mb
//     (64 VGPR), acc 64 AGPR -> ~220 regs, no spill (R10 had 141MB scratch).
//   * superstep: vmcnt(8) + lgkmcnt(0) -> issue A ss+1 (8 ds_b128) ->
//     setprio(1) 16 MFMA setprio(0) -> issue W ss+2 (8 asm globals).
//   * cross-barrier prefetch: 2 W-supersteps issued before each h barrier
//     (drain-free lgkm-only barriers from R10 kept).
__global__ __launch_bounds__(512, 2) void mesh_main(
    const float* __restrict__ W0, const float* __restrict__ b1,
    const float* __restrict__ b2, const float* __restrict__ W3,
    const float* __restrict__ b3, const float* __restrict__ latw,
    const _Float16* __restrict__ wsB, float* __restrict__ out) {

    __shared__ _Float16 hbuf2[4096 * 8];          // 64 KB, fragment-major h
    __shared__ float lwbuf[2 * H];                // 4 KB
    __shared__ float partials[8][MTILE];          // 2 KB  -> 70 KB total

    const int tid = threadIdx.x;
    const int wave = tid >> 6, lane = tid & 63;
    const int lm = lane & 31, hi = lane >> 5;
    const int uwave = __builtin_amdgcn_readfirstlane(wave);  // force SGPR
    const int bi = blockIdx.x;
    const int b = bi >> 12;
    const int p0 = (bi & 4095) << 6;              // 64 rows per block (fixed x,y)
    const float c0 = -1.2f + (float)(p0 >> 12) * STEPC;
    const float c1 = -1.2f + (float)((p0 >> 6) & 63) * STEPC;

    // drain-free phase barrier: orders LDS only; vmcnt queue stays in flight
    auto phase_barrier = [&]() {
        __builtin_amdgcn_sched_barrier(0);
        asm volatile("s_waitcnt lgkmcnt(0)" ::: "memory");
        __builtin_amdgcn_s_barrier();
        __builtin_amdgcn_sched_barrier(0);
    };

    // per-lane bases
    const int vWoffB = hi * 32768 + lm * 16;             // W: loop-constant byte voffset
    const _Float16* hb = hbuf2 + hi * 512 + lm * 8;      // A: LDS base, imm offsets

    floatx16 acc[2][2];

    auto zero_acc = [&]() {
#pragma unroll
        for (int mb = 0; mb < 2; ++mb)
#pragma unroll
            for (int nt = 0; nt < 2; ++nt)
#pragma unroll
                for (int r = 0; r < 16; ++r) acc[mb][nt][r] = 0.f;
    };

    // asm-pinned W-fragment load pair: saddr uniform, voffset constant, imm nt
    auto issueW = [&](const _Float16* base, int ks, half8 (&wf)[2]) {
        const _Float16* sp = base + ks * 512;            // uniform (SALU add)
        asm volatile("global_load_dwordx4 %0, %2, %3\n\t"
                     "global_load_dwordx4 %1, %2, %3 offset:512"
                     : "=v"(wf[0]), "=v"(wf[1])
                     : "v"(vWoffB), "s"(sp)
                     : "memory");
    };

    auto loadA = [&](int ks, half8 (&a)[2]) {
        const _Float16* hp = hb + ks * 1024;
        a[0] = *(const half8*)(hp);            // mb=0, pure offset-imm ds_read
        a[1] = *(const half8*)(hp + 256);      // mb=1
    };

    // superstep-granular issue helpers (4 ks each)
    auto issueWss = [&](const _Float16* base, int ss, half8 (&Wbuf)[4][2]) {
#pragma unroll
        for (int k = 0; k < 4; ++k) issueW(base, ss * 4 + k, Wbuf[k]);
    };
    auto issueAss = [&](int ss, half8 (&Abuf)[4][2]) {
#pragma unroll
        for (int k = 0; k < 4; ++k) loadA(ss * 4 + k, Abuf[k]);
    };

    auto compute = [&](half8 (&wf)[2], half8 (&a)[2]) {
#pragma unroll
        for (int nt = 0; nt < 2; ++nt)
#pragma unroll
            for (int mb = 0; mb < 2; ++mb)
                acc[mb][nt] = __builtin_amdgcn_mfma_f32_32x32x16_f16(wf[nt], a[mb], acc[mb][nt], 0, 0, 0);
    };

    const _Float16* wbase0 = wsB + (size_t)uwave * 32768;         // GEMM1 (W1)
    const _Float16* wbase1 = wsB + (size_t)(8 + uwave) * 32768;   // GEMM2 (W2)

    half8 Wq[2][4][2];     // [ss parity][ks-in-ss][nt]: 64 VGPR
    half8 Aq[2][4][2];     // [ss parity][ks-in-ss][mb]: 64 VGPR

    // K-loop body: assumes W supersteps 0,1 already in flight (pre-barrier).
    // 8 supersteps x {counted waits -> issue A ss+1 -> 16-MFMA burst ->
    // issue W ss+2}. vmcnt never 0 until the last superstep.
    auto run_gemm_body = [&](const _Float16* base) {
        issueAss(0, Aq[0]);
#pragma unroll
        for (int s = 0; s < 8; ++s) {
            if (s < 7) asm volatile("s_waitcnt vmcnt(8)" ::: "memory");
            else       asm volatile("s_waitcnt vmcnt(0)" ::: "memory");
            asm volatile("s_waitcnt lgkmcnt(0)" ::: "memory");
            __builtin_amdgcn_sched_barrier(0);
            if (s + 1 < 8) issueAss(s + 1, Aq[(s + 1) & 1]);   // lands under burst
            __builtin_amdgcn_sched_barrier(0);
            __builtin_amdgcn_s_setprio(1);
#pragma unroll
            for (int k = 0; k < 4; ++k)
                compute(Wq[s & 1][k], Aq[s & 1][k]);
            __builtin_amdgcn_s_setprio(0);
            __builtin_amdgcn_sched_barrier(0);
            if (s + 2 < 8) issueWss(base, s + 2, Wq[s & 1]);   // slot just consumed
        }
    };

    // ---- layer 0, phase A: lw[j] = latw + c0*W0x + c1*W0y; w2c[j] = W0z ----
    {
        const int j = tid;
        const float lwv = latw[b * H + j]
                        + c0 * W0[(H + 0) * H + j]
                        + c1 * W0[(H + 1) * H + j];
        floatx2 v;
        v[0] = lwv;
        v[1] = W0[(H + 2) * H + j];
        *(floatx2*)&lwbuf[2 * j] = v;
    }
    phase_barrier();

    // ---- layer 0, phase B: row m = lane; regions g = wave*8+s ----
    {
        const float c2v = -1.2f + (float)lane * STEPC;
#pragma unroll
        for (int s = 0; s < 8; ++s) {
            const int g = wave * 8 + s;
            const floatx4* lp = (const floatx4*)&lwbuf[g * 16];  // broadcast reads
            half8 hv;
#pragma unroll
            for (int i = 0; i < 4; ++i) {
                const floatx4 pv = lp[i];          // (lw, w2c, lw, w2c)
                hv[2 * i + 0] = (_Float16)silu_f(pv[0] + c2v * pv[1]);
                hv[2 * i + 1] = (_Float16)silu_f(pv[2] + c2v * pv[3]);
            }
            *(half8*)&hbuf2[(g * 64 + lane) * 8] = hv;
        }
    }
    zero_acc();
    // G1 prefetch: 2 W supersteps issued now; survive the drain-free barrier.
    __builtin_amdgcn_sched_barrier(0);
    issueWss(wbase0, 0, Wq[0]);
    issueWss(wbase0, 1, Wq[1]);
    phase_barrier();             // h0 ready

    // ---- GEMM 1 ----
    run_gemm_body(wbase0);
    phase_barrier();             // all waves done reading h0

    // writeback h1 = silu(acc + b1): lane owns, per (mb,nt,g), 4 consecutive
    // n = wave*64 + nt*32 + g*8 + hi*4 .. +3 at row m = mb*32+lm -> b64 writes
    {
        _Float16* wb = hbuf2 + (wave * 8) * 512 + lm * 8 + hi * 4;
        floatx4 b1v[2][4];
#pragma unroll
        for (int nt = 0; nt < 2; ++nt)
#pragma unroll
            for (int g = 0; g < 4; ++g)
                b1v[nt][g] = *(const floatx4*)&b1[wave * 64 + nt * 32 + g * 8 + hi * 4];
#pragma unroll
        for (int mb = 0; mb < 2; ++mb)
#pragma unroll
            for (int nt = 0; nt < 2; ++nt)
#pragma unroll
                for (int g = 0; g < 4; ++g) {
                    half4_t hv;
#pragma unroll
                    for (int j = 0; j < 4; ++j)
                        hv[j] = (_Float16)silu_f(acc[mb][nt][g * 4 + j] + b1v[nt][g][j]);
                    *(half4_t*)(wb + (nt * 4 + g) * 512 + mb * 256) = hv;
                }
    }
    zero_acc();
    // G2 prefetch: b1 uses precede (compiler-ordered) -> queue is clean.
    __builtin_amdgcn_sched_barrier(0);
    issueWss(wbase1, 0, Wq[0]);
    issueWss(wbase1, 1, Wq[1]);
    phase_barrier();             // h1 ready

    // ---- GEMM 2 ----
    run_gemm_body(wbase1);

    // ---- final layer: out = silu(acc + b2) @ W3 + b3, fp32 VALU ----
    {
        floatx4 b2v[2][4], w3v[2][4];
#pragma unroll
        for (int nt = 0; nt < 2; ++nt)
#pragma unroll
            for (int g = 0; g < 4; ++g) {
                const int n0 = wave * 64 + nt * 32 + g * 8 + hi * 4;
                b2v[nt][g] = *(const floatx4*)&b2[n0];
                w3v[nt][g] = *(const floatx4*)&W3[n0];
            }
#pragma unroll
        for (int mb = 0; mb < 2; ++mb) {
            float sum = 0.f;
#pragma unroll
            for (int nt = 0; nt < 2; ++nt)
#pragma unroll
                for (int g = 0; g < 4; ++g)
#pragma unroll
                    for (int j = 0; j < 4; ++j)
                        sum += silu_f(acc[mb][nt][g * 4 + j] + b2v[nt][g][j]) * w3v[nt][g][j];
            sum += __shfl_xor(sum, 32);        // combine hi halves (same m)
            if (hi == 0) partials[wave][mb * 32 + lm] = sum;
        }
    }
    phase_barrier();
    if (tid < MTILE) {
        float o = b3[0];
#pragma unroll
        for (int w = 0; w < 8; ++w) o += partials[w][tid];
        out[(size_t)bi * MTILE + tid] = o;
    }
}

extern "C" void kernel_launch(void* const* d_in, const int* in_sizes, int n_in,
                              void* d_out, int out_size, void* d_ws, size_t ws_size,
                              hipStream_t stream) {
    const float* lat = (const float*)d_in[0];
    const float* W0  = (const float*)d_in[1];
    const float* b0  = (const float*)d_in[2];
    const float* W1  = (const float*)d_in[3];
    const float* b1  = (const float*)d_in[4];
    const float* W2  = (const float*)d_in[5];
    const float* b2  = (const float*)d_in[6];
    const float* W3  = (const float*)d_in[7];
    const float* b3  = (const float*)d_in[8];
    float* out = (float*)d_out;

    float* latw = (float*)d_ws;                               // 4 KB
    _Float16* wsB = (_Float16*)((char*)d_ws + 4096);          // 1 MB

    prep_fused<<<1026, 512, 0, stream>>>(lat, W0, b0, W1, W2, latw, wsB);
    mesh_main<<<NBLK, 512, 0, stream>>>(W0, b1, b2, W3, b3, latw, wsB, out);
}

// Round 13
// 778.848 us; speedup vs baseline: 1.0586x; 1.0586x over previous
//
#include <hip/hip_runtime.h>

#define H 512
#define MTILE 64
#define NBLK 8192
#define STEPC (2.4f / 63.0f)

typedef _Float16 half8 __attribute__((ext_vector_type(8)));
typedef _Float16 half4_t __attribute__((ext_vector_type(4)));
typedef float floatx16 __attribute__((ext_vector_type(16)));
typedef float floatx4 __attribute__((ext_vector_type(4)));
typedef float floatx2 __attribute__((ext_vector_type(2)));

// fast silu: native exp + fast div. rel-err ~1e-7, negligible vs fp16 rounding.
__device__ inline float silu_f(float x) {
    return __fdividef(x, 1.0f + __expf(-x));
}

// ---- fused prep: blocks 0..1023 -> W image; blocks 1024..1025 -> latw ----
// W image layout: [l][wv][hi][ks][nt][lm][e]  (halves)
//   idx = (l*8+wv)*32768 + hi*16384 + ks*512 + nt*256 + lm*8 + e
__global__ void prep_fused(const float* __restrict__ lat, const float* __restrict__ W0,
                           const float* __restrict__ b0,
                           const float* __restrict__ W1, const float* __restrict__ W2,
                           float* __restrict__ latw, _Float16* __restrict__ ws,
                           int* __restrict__ cnt) {
    __shared__ float sl[H];
    if (blockIdx.x < 1024) {
        const int id = blockIdx.x * 512 + threadIdx.x;   // 0 .. 524287
        const int l = id >> 18;
        const int rem = id & 0x3FFFF;                    // k*512 + n
        const int k = rem >> 9, n = rem & 511;
        const float w = (l == 0 ? W1 : W2)[rem];
        const int ks = k >> 4, hi = (k >> 3) & 1, e = k & 7;
        const int wv = n >> 6, nt = (n >> 5) & 1, lm = n & 31;
        ws[(size_t)(l * 8 + wv) * 32768 + hi * 16384 + ks * 512 + nt * 256 + lm * 8 + e]
            = (_Float16)w;
    } else {
        const int b = blockIdx.x - 1024;
        if (b == 0 && threadIdx.x == 0) *cnt = 0;        // stagger ticket reset
        const int j = threadIdx.x;
        sl[j] = lat[b * H + j];
        __syncthreads();
        float acc = b0[j];
#pragma unroll 8
        for (int d = 0; d < H; ++d) acc += sl[d] * W0[d * H + j];
        latw[b * H + j] = acc;
    }
}

// ---- main fused kernel ----
// R13: R10 (best, 734us steady) + PER-CU PHASE STAGGER.
// R10/R11/R12 pinned the serialized-sum model: per CU-round the MFMA,
// L2-W, LDS-A and VALU demands add nearly perfectly (model 111.6K vs
// measured 110K cyc) even though m114 proves MFMA-wave || VALU-wave
// co-scheduling works when roles differ. Hypothesis: the 2 co-resident
// blocks launch together, run symmetric code, and stay PHASE-LOCKED, so
// block B's silu phases never hide under block A's K-loop. Test: global
// ticket; first-fill blocks (t<512) with parity (t&1)^((t>>8)&1) (covers
// CU-major and slot-major fills) sleep ~32K cyc once, right after the
// first barrier -> pairs run anti-phase; slots refill staggered forever.
// Cost ~1.1%. Everything else byte-identical to R10 (asm W queue, counted
// vmcnt, drain-free lgkm-only barriers, cross-barrier prefetch, setprio).
__global__ __launch_bounds__(512, 4) void mesh_main(
    const float* __restrict__ W0, const float* __restrict__ b1,
    const float* __restrict__ b2, const float* __restrict__ W3,
    const float* __restrict__ b3, const float* __restrict__ latw,
    const _Float16* __restrict__ wsB, float* __restrict__ out,
    int* __restrict__ cnt) {

    __shared__ _Float16 hbuf2[4096 * 8];          // 64 KB, fragment-major h
    __shared__ float lwbuf[2 * H];                // 4 KB
    __shared__ float partials[8][MTILE];          // 2 KB
    __shared__ int sflag;                         // stagger flag

    const int tid = threadIdx.x;
    const int wave = tid >> 6, lane = tid & 63;
    const int lm = lane & 31, hi = lane >> 5;
    const int uwave = __builtin_amdgcn_readfirstlane(wave);  // force SGPR
    const int bi = blockIdx.x;
    const int b = bi >> 12;
    const int p0 = (bi & 4095) << 6;              // 64 rows per block (fixed x,y)
    const float c0 = -1.2f + (float)(p0 >> 12) * STEPC;
    const float c1 = -1.2f + (float)((p0 >> 6) & 63) * STEPC;

    // drain-free phase barrier: orders LDS only; vmcnt queue stays in flight
    auto phase_barrier = [&]() {
        __builtin_amdgcn_sched_barrier(0);
        asm volatile("s_waitcnt lgkmcnt(0)" ::: "memory");
        __builtin_amdgcn_s_barrier();
        __builtin_amdgcn_sched_barrier(0);
    };

    // per-lane bases
    const int vWoffB = hi * 32768 + lm * 16;             // W: loop-constant byte voffset
    const _Float16* hb = hbuf2 + hi * 512 + lm * 8;      // A: LDS base, imm offsets

    floatx16 acc[2][2];

    auto zero_acc = [&]() {
#pragma unroll
        for (int mb = 0; mb < 2; ++mb)
#pragma unroll
            for (int nt = 0; nt < 2; ++nt)
#pragma unroll
                for (int r = 0; r < 16; ++r) acc[mb][nt][r] = 0.f;
    };

    // asm-pinned W-fragment load pair: saddr uniform, voffset constant, imm nt
    auto issueW = [&](const _Float16* base, int ks, half8 (&wf)[2]) {
        const _Float16* sp = base + ks * 512;            // uniform (SALU add)
        asm volatile("global_load_dwordx4 %0, %2, %3\n\t"
                     "global_load_dwordx4 %1, %2, %3 offset:512"
                     : "=v"(wf[0]), "=v"(wf[1])
                     : "v"(vWoffB), "s"(sp)
                     : "memory");
    };

    auto loadA = [&](int ks, half8 (&a)[2]) {
        const _Float16* hp = hb + ks * 1024;
        a[0] = *(const half8*)(hp);            // mb=0, pure offset-imm ds_read
        a[1] = *(const half8*)(hp + 256);      // mb=1
    };

    auto compute = [&](half8 (&wf)[2], half8 (&a)[2]) {
        __builtin_amdgcn_s_setprio(1);
#pragma unroll
        for (int nt = 0; nt < 2; ++nt)
#pragma unroll
            for (int mb = 0; mb < 2; ++mb)
                acc[mb][nt] = __builtin_amdgcn_mfma_f32_32x32x16_f16(wf[nt], a[mb], acc[mb][nt], 0, 0, 0);
        __builtin_amdgcn_s_setprio(0);
    };

    const _Float16* wbase0 = wsB + (size_t)uwave * 32768;         // GEMM1 (W1)
    const _Float16* wbase1 = wsB + (size_t)(8 + uwave) * 32768;   // GEMM2 (W2)

    half8 Wq[3][2];        // shared W queue across both GEMMs

    // K-loop body: assumes chunks 0..2 already in flight (issued pre-barrier).
    auto run_gemm_body = [&](const _Float16* base) {
        half8 Aq[2][2];
        loadA(0, Aq[0]);
        loadA(1, Aq[1]);
#pragma unroll
        for (int ks = 0; ks < 32; ++ks) {       // fully unrolled, static indices
            if (ks <= 29)      asm volatile("s_waitcnt vmcnt(4)" ::: "memory");
            else if (ks == 30) asm volatile("s_waitcnt vmcnt(2)" ::: "memory");
            else               asm volatile("s_waitcnt vmcnt(0)" ::: "memory");
            __builtin_amdgcn_sched_barrier(0);
            compute(Wq[ks % 3], Aq[ks % 2]);
            if (ks + 3 < 32) issueW(base, ks + 3, Wq[ks % 3]);   // slot just consumed
            if (ks + 2 < 32) loadA(ks + 2, Aq[ks % 2]);          // compiler-ordered
        }
    };

    // ---- stagger ticket (tid 0) + layer 0, phase A ----
    if (tid == 0) {
        const int t = atomicAdd(cnt, 1);
        // one-time, first fill only; parity robust to CU-major or slot-major
        sflag = (t < 512) && (((t & 1) ^ ((t >> 8) & 1)) != 0);
    }
    {
        const int j = tid;
        const float lwv = latw[b * H + j]
                        + c0 * W0[(H + 0) * H + j]
                        + c1 * W0[(H + 1) * H + j];
        floatx2 v;
        v[0] = lwv;
        v[1] = W0[(H + 2) * H + j];
        *(floatx2*)&lwbuf[2 * j] = v;
    }
    phase_barrier();

    // ---- phase stagger: anti-phase the two co-resident blocks ----
    if (sflag) {
#pragma unroll 1
        for (int i = 0; i < 4; ++i) __builtin_amdgcn_s_sleep(127);  // ~32K cyc
    }

    // ---- layer 0, phase B: row m = lane; regions g = wave*8+s ----
    {
        const float c2v = -1.2f + (float)lane * STEPC;
#pragma unroll
        for (int s = 0; s < 8; ++s) {
            const int g = wave * 8 + s;
            const floatx4* lp = (const floatx4*)&lwbuf[g * 16];  // broadcast reads
            half8 hv;
#pragma unroll
            for (int i = 0; i < 4; ++i) {
                const floatx4 pv = lp[i];          // (lw, w2c, lw, w2c)
                hv[2 * i + 0] = (_Float16)silu_f(pv[0] + c2v * pv[1]);
                hv[2 * i + 1] = (_Float16)silu_f(pv[2] + c2v * pv[3]);
            }
            *(half8*)&hbuf2[(g * 64 + lane) * 8] = hv;
        }
    }
    zero_acc();
    // G1 prefetch: issued pre-barrier; survives it (no vmcnt drain).
    __builtin_amdgcn_sched_barrier(0);
    issueW(wbase0, 0, Wq[0]);
    issueW(wbase0, 1, Wq[1]);
    issueW(wbase0, 2, Wq[2]);
    phase_barrier();             // h0 ready

    // ---- GEMM 1 ----
    run_gemm_body(wbase0);
    phase_barrier();             // all waves done reading h0

    // writeback h1 = silu(acc + b1): lane owns, per (mb,nt,g), 4 consecutive
    // n = wave*64 + nt*32 + g*8 + hi*4 .. +3 at row m = mb*32+lm -> b64 writes
    {
        _Float16* wb = hbuf2 + (wave * 8) * 512 + lm * 8 + hi * 4;
        floatx4 b1v[2][4];
#pragma unroll
        for (int nt = 0; nt < 2; ++nt)
#pragma unroll
            for (int g = 0; g < 4; ++g)
                b1v[nt][g] = *(const floatx4*)&b1[wave * 64 + nt * 32 + g * 8 + hi * 4];
#pragma unroll
        for (int mb = 0; mb < 2; ++mb)
#pragma unroll
            for (int nt = 0; nt < 2; ++nt)
#pragma unroll
                for (int g = 0; g < 4; ++g) {
                    half4_t hv;
#pragma unroll
                    for (int j = 0; j < 4; ++j)
                        hv[j] = (_Float16)silu_f(acc[mb][nt][g * 4 + j] + b1v[nt][g][j]);
                    *(half4_t*)(wb + (nt * 4 + g) * 512 + mb * 256) = hv;
                }
    }
    zero_acc();
    // G2 prefetch: b1 uses precede (compiler-ordered) -> queue is clean.
    __builtin_amdgcn_sched_barrier(0);
    issueW(wbase1, 0, Wq[0]);
    issueW(wbase1, 1, Wq[1]);
    issueW(wbase1, 2, Wq[2]);
    phase_barrier();             // h1 ready

    // ---- GEMM 2 ----
    run_gemm_body(wbase1);

    // ---- final layer: out = silu(acc + b2) @ W3 + b3, fp32 VALU ----
    {
        floatx4 b2v[2][4], w3v[2][4];
#pragma unroll
        for (int nt = 0; nt < 2; ++nt)
#pragma unroll
            for (int g = 0; g < 4; ++g) {
                const int n0 = wave * 64 + nt * 32 + g * 8 + hi * 4;
                b2v[nt][g] = *(const floatx4*)&b2[n0];
                w3v[nt][g] = *(const floatx4*)&W3[n0];
            }
#pragma unroll
        for (int mb = 0; mb < 2; ++mb) {
            float sum = 0.f;
#pragma unroll
            for (int nt = 0; nt < 2; ++nt)
#pragma unroll
                for (int g = 0; g < 4; ++g)
#pragma unroll
                    for (int j = 0; j < 4; ++j)
                        sum += silu_f(acc[mb][nt][g * 4 + j] + b2v[nt][g][j]) * w3v[nt][g][j];
            sum += __shfl_xor(sum, 32);        // combine hi halves (same m)
            if (hi == 0) partials[wave][mb * 32 + lm] = sum;
        }
    }
    phase_barrier();
    if (tid < MTILE) {
        float o = b3[0];
#pragma unroll
        for (int w = 0; w < 8; ++w) o += partials[w][tid];
        out[(size_t)bi * MTILE + tid] = o;
    }
}

extern "C" void kernel_launch(void* const* d_in, const int* in_sizes, int n_in,
                              void* d_out, int out_size, void* d_ws, size_t ws_size,
                              hipStream_t stream) {
    const float* lat = (const float*)d_in[0];
    const float* W0  = (const float*)d_in[1];
    const float* b0  = (const float*)d_in[2];
    const float* W1  = (const float*)d_in[3];
    const float* b1  = (const float*)d_in[4];
    const float* W2  = (const float*)d_in[5];
    const float* b2  = (const float*)d_in[6];
    const float* W3  = (const float*)d_in[7];
    const float* b3  = (const float*)d_in[8];
    float* out = (float*)d_out;

    float* latw = (float*)d_ws;                               // 4 KB
    _Float16* wsB = (_Float16*)((char*)d_ws + 4096);          // 1 MB
    int* cnt = (int*)((char*)d_ws + 4096 + (1 << 20));        // 4 B ticket

    prep_fused<<<1026, 512, 0, stream>>>(lat, W0, b0, W1, W2, latw, wsB, cnt);
    mesh_main<<<NBLK, 512, 0, stream>>>(W0, b1, b2, W3, b3, latw, wsB, out, cnt);
}